// Round 5
// baseline (3124.812 us; speedup 1.0000x reference)
//
#include <hip/hip_runtime.h>
#include <hip/hip_bf16.h>
#include <math.h>

#define VB 50000
#define EE 256
#define UU 512
#define BB 256
#define TT 256
#define G4 2048

typedef __attribute__((ext_vector_type(8))) short short8;
typedef __attribute__((ext_vector_type(4))) float f32x4;

__device__ __forceinline__ float sigf(float x){ return 1.0f/(1.0f+expf(-x)); }
__device__ __forceinline__ unsigned short f2bf(float f){
    __hip_bfloat16 h = __float2bfloat16(f);   // RNE
    unsigned short s; __builtin_memcpy(&s,&h,2); return s;
}
__device__ __forceinline__ float bf2f(unsigned short u){
    unsigned int x = ((unsigned int)u)<<16; float f; __builtin_memcpy(&f,&x,4); return f;
}

// 16-byte device-coherent load as 2x8B agent-scope relaxed atomics (bypass
// stale per-CU L1 / per-XCD L2; served at the coherent point).
struct AF { unsigned long long a, b; };
__device__ __forceinline__ AF cload16(const unsigned short* p){
    const unsigned long long* q = (const unsigned long long*)p;
    AF r;
    r.a = __hip_atomic_load(q,   __ATOMIC_RELAXED, __HIP_MEMORY_SCOPE_AGENT);
    r.b = __hip_atomic_load(q+1, __ATOMIC_RELAXED, __HIP_MEMORY_SCOPE_AGENT);
    return r;
}
__device__ __forceinline__ short8 af2v(AF x){
    union { unsigned long long u[2]; short8 v; } c; c.u[0]=x.a; c.u[1]=x.b; return c.v;
}
__device__ __forceinline__ unsigned int cldu(const unsigned int* p){
    return __hip_atomic_load(p, __ATOMIC_RELAXED, __HIP_MEMORY_SCOPE_AGENT);
}
__device__ __forceinline__ void cstu(unsigned int* p, unsigned int v){
    __hip_atomic_store(p, v, __ATOMIC_RELAXED, __HIP_MEMORY_SCOPE_AGENT);
}

// ---------- pre-pass: transpose+convert W [rows][2048] fp32 -> out[c][koff+k] bf16 ----------
__global__ __launch_bounds__(256) void wtrans(const float* __restrict__ in, int rows,
                                              unsigned short* __restrict__ out,
                                              int Kout, int koff) {
    __shared__ float tl[32][33];
    int tx = threadIdx.x, ty = threadIdx.y;
    int c0 = blockIdx.x * 32, k0 = blockIdx.y * 32;
    #pragma unroll
    for (int i = 0; i < 4; i++)
        tl[ty + i * 8][tx] = in[(size_t)(k0 + ty + i * 8) * G4 + c0 + tx];
    __syncthreads();
    #pragma unroll
    for (int i = 0; i < 4; i++)
        out[(size_t)(c0 + ty + i * 8) * Kout + koff + k0 + tx] = f2bf(tl[tx][ty + i * 8]);
}

// ---------- pre-pass: gather embeddings -> xbf[t][b][k] bf16 ----------
__global__ __launch_bounds__(64) void xgather(const int* __restrict__ tokens,
                                              const float* __restrict__ emb,
                                              unsigned short* __restrict__ xbf) {
    int flat = blockIdx.x;
    int b = flat & 255, t = flat >> 8;
    int tok = tokens[b * TT + t];
    float4 v = ((const float4*)(emb + (size_t)tok * EE))[threadIdx.x];
    ushort4 o;
    o.x = f2bf(v.x); o.y = f2bf(v.y); o.z = f2bf(v.z); o.w = f2bf(v.w);
    ((ushort4*)(xbf + ((size_t)t * BB + b) * EE))[threadIdx.x] = o;
}

// ---------- persistent 2-layer LSTM ----------
// 4 groups x 64 blocks; group g owns batch rows [g*64, g*64+64).
// local 0..31 = layer0 (K=768: x|h0), 32..63 = layer1 (K=1024: h0|h1); 16 u's/block.
// Weights LDS-resident. c-state in registers. h via agent-scope relaxed atomics.
// PER-LAYER split barriers: arrival slots padded to 64B; L0 leader (local==0)
// publishes go0 after [all arr0 >= p && go1 >= p-2] (h0 ring depth-4 flow ctl);
// L1 leader (local==32) publishes go1 after [all arr1 >= p && go0 >= p].
// Followers spin one word. L0's x-part MFMAs run BEFORE the release-wait.
__global__ __launch_bounds__(256, 1) void rnn_persist(
    const unsigned short* __restrict__ Wt0,   // [2048][768]  bf16 [col][k]
    const unsigned short* __restrict__ Wt1,   // [2048][1024]
    const unsigned short* __restrict__ xbf,   // [256][256][256] bf16 (or unused)
    const int* __restrict__ tokens, const float* __restrict__ emb,
    const float* __restrict__ b0v, const float* __restrict__ b1v,
    unsigned short* __restrict__ h0buf,       // [4][256][512] bf16 ring
    unsigned short* __restrict__ h1buf,       // [2][256][512] bf16 ring
    unsigned int* __restrict__ bars,          // per group 2048 uints (8KB)
    int use_xbf)
{
    extern __shared__ char smem[];
    unsigned short* wl  = (unsigned short*)smem;               // frag-ordered weights (<=128KB)
    unsigned short* hst = (unsigned short*)(smem + 131072);    // 64x16 h staging (2KB)
    int*            tokl = (int*)(smem + 131072 + 2048);       // 64 ints

    const int tid   = threadIdx.x;
    const int bid   = blockIdx.x;
    const int g     = bid >> 6;
    const int local = bid & 63;
    const int layer = local >> 5;
    const int u0    = (local & 31) * 16;
    const int row0  = g * 64;
    const int K     = layer ? 1024 : 768;
    const int KT    = K / 32;                  // 24 or 32 k-tiles
    const unsigned short* Wt = layer ? Wt1 : Wt0;
    const float* bR = layer ? b1v : b0v;

    // ---- fill LDS weights, frag-contiguous: chunk i = ((gate*KT+kt)*64 + (n*4+q)) ----
    const int nch = 4 * KT * 64;
    for (int i = tid; i < nch; i += 256) {
        int q  = i & 3;
        int n  = (i >> 2) & 15;
        int t2 = i >> 6;
        int kt = t2 % KT, gate = t2 / KT;
        const unsigned short* src = Wt + (size_t)(gate * UU + u0 + n) * K + kt * 32 + q * 8;
        *(short8*)(wl + (size_t)i * 8) = *(const short8*)src;
    }

    float gb[4];
    #pragma unroll
    for (int gate = 0; gate < 4; gate++) gb[gate] = bR[gate * UU + u0 + (tid & 15)];
    float cst[4] = {0.f, 0.f, 0.f, 0.f};

    const int lane = tid & 63;
    const int w    = tid >> 6;
    const int n16  = lane & 15;
    const int q    = lane >> 4;
    const int q8   = q * 8;
    const int myrow = row0 + w * 16 + n16;
    const unsigned short* wlane = wl + (n16 * 4 + q) * 8;   // + (gate*KT+kt)*512 shorts

    // barrier region for this group: arr slots 64B apart; go words on own lines
    unsigned int* gb4  = bars + (size_t)g * 2048;
    unsigned int* myArr = gb4 + (layer ? 512 : 0) + (local & 31) * 16;
    unsigned int* go0  = gb4 + 1536;
    unsigned int* go1  = gb4 + 1552;

    const size_t HS = (size_t)BB * UU;

    __syncthreads();   // wl ready

    for (int p = 0; p <= TT; p++) {
        const bool active = layer ? (p >= 1) : (p < TT);

        f32x4 acc[4];
        #pragma unroll
        for (int gate = 0; gate < 4; gate++) acc[gate] = (f32x4){0.f, 0.f, 0.f, 0.f};

        // ---- L0 x-part precompute (static inputs only) BEFORE release-wait ----
        if (layer == 0 && p < TT) {
            if (!use_xbf) {
                if (tid < 64) tokl[tid] = tokens[(size_t)(row0 + tid) * TT + p];
                __syncthreads();
                const float* ep = emb + (size_t)tokl[w * 16 + n16] * EE + q8;
                #pragma unroll
                for (int kt = 0; kt < 8; kt++) {
                    float4 f0 = *(const float4*)(ep + kt * 32);
                    float4 f1 = *(const float4*)(ep + kt * 32 + 4);
                    union { unsigned short s[8]; short8 v; } u;
                    u.s[0]=f2bf(f0.x); u.s[1]=f2bf(f0.y); u.s[2]=f2bf(f0.z); u.s[3]=f2bf(f0.w);
                    u.s[4]=f2bf(f1.x); u.s[5]=f2bf(f1.y); u.s[6]=f2bf(f1.z); u.s[7]=f2bf(f1.w);
                    #pragma unroll
                    for (int gate = 0; gate < 4; gate++) {
                        short8 bv = *(const short8*)(wlane + (size_t)(gate * KT + kt) * 512);
                        acc[gate] = __builtin_amdgcn_mfma_f32_16x16x32_bf16(u.v, bv, acc[gate], 0, 0, 0);
                    }
                }
            } else {
                const unsigned short* xp = xbf + ((size_t)p * BB + myrow) * EE + q8;
                #pragma unroll
                for (int kt = 0; kt < 8; kt++) {
                    short8 av = *(const short8*)(xp + kt * 32);
                    #pragma unroll
                    for (int gate = 0; gate < 4; gate++) {
                        short8 bv = *(const short8*)(wlane + (size_t)(gate * KT + kt) * 512);
                        acc[gate] = __builtin_amdgcn_mfma_f32_16x16x32_bf16(av, bv, acc[gate], 0, 0, 0);
                    }
                }
            }
        }

        // ---- release-wait for phase p ----
        if (local == 0) {              // L0 leader
            if (tid < 64) {
                for (;;) {
                    bool bad = false;
                    if (tid < 32)       bad = ((int)cldu(gb4 + tid * 16) < p);
                    else if (tid == 32) bad = ((int)cldu(go1) < p - 2);
                    if (__ballot(bad) == 0ULL) break;
                    __builtin_amdgcn_s_sleep(1);
                }
                if (tid == 0) cstu(go0, (unsigned int)p);
            }
        } else if (local == 32) {      // L1 leader
            if (tid < 64) {
                for (;;) {
                    bool bad = false;
                    if (tid < 32)       bad = ((int)cldu(gb4 + 512 + tid * 16) < p);
                    else if (tid == 32) bad = ((int)cldu(go0) < p);
                    if (__ballot(bad) == 0ULL) break;
                    __builtin_amdgcn_s_sleep(1);
                }
                if (tid == 0) cstu(go1, (unsigned int)p);
            }
        } else {
            if (tid == 0) {
                unsigned int* gw = layer ? go1 : go0;
                while ((int)cldu(gw) < p) __builtin_amdgcn_s_sleep(1);
            }
        }
        __syncthreads();

        // ---- dynamic (h-dependent) part ----
        if (active) {
            const unsigned short* h0r = h0buf + (size_t)(p & 3) * HS;
            unsigned short* hw;

            if (layer) {
                const unsigned short* h1r = h1buf + (size_t)((p + 1) & 1) * HS;  // h1(p-1)
                hw = h1buf + (size_t)(p & 1) * HS;
                const unsigned short* a0 = h0r + (size_t)myrow * UU + q8;
                const unsigned short* a1 = h1r + (size_t)myrow * UU + q8;
                AF ab[2][16];
                #pragma unroll
                for (int i = 0; i < 16; i++) ab[0][i] = cload16(a0 + i * 32);
                #pragma unroll
                for (int i = 0; i < 16; i++) ab[1][i] = cload16(a1 + i * 32);
                #pragma unroll
                for (int half = 0; half < 2; half++) {
                    #pragma unroll
                    for (int i = 0; i < 16; i++) {
                        int kt = half * 16 + i;
                        short8 av = af2v(ab[half][i]);
                        #pragma unroll
                        for (int gate = 0; gate < 4; gate++) {
                            short8 bv = *(const short8*)(wlane + (size_t)(gate * KT + kt) * 512);
                            acc[gate] = __builtin_amdgcn_mfma_f32_16x16x32_bf16(av, bv, acc[gate], 0, 0, 0);
                        }
                    }
                }
            } else {
                hw = h0buf + (size_t)((p + 1) & 3) * HS;
                const unsigned short* ah = h0r + (size_t)myrow * UU + q8;
                AF ab[16];
                #pragma unroll
                for (int i = 0; i < 16; i++) ab[i] = cload16(ah + i * 32);
                #pragma unroll
                for (int i = 0; i < 16; i++) {
                    int kt = 8 + i;
                    short8 av = af2v(ab[i]);
                    #pragma unroll
                    for (int gate = 0; gate < 4; gate++) {
                        short8 bv = *(const short8*)(wlane + (size_t)(gate * KT + kt) * 512);
                        acc[gate] = __builtin_amdgcn_mfma_f32_16x16x32_bf16(av, bv, acc[gate], 0, 0, 0);
                    }
                }
            }

            // gating (D layout: col=n16 -> u, row=q*4+r); stage h to LDS
            #pragma unroll
            for (int r = 0; r < 4; r++) {
                float zi = acc[0][r] + gb[0];
                float zf = acc[1][r] + gb[1];
                float zg = acc[2][r] + gb[2];
                float zo = acc[3][r] + gb[3];
                float cn = sigf(zf) * cst[r] + sigf(zi) * tanhf(zg);
                cst[r] = cn;
                hst[(w * 16 + q * 4 + r) * 16 + n16] = f2bf(sigf(zo) * tanhf(cn));
            }
            __syncthreads();   // block-uniform
            if (tid < 128) {   // coalesced coherent store: 128 threads x 16B
                int row = tid >> 1, half = tid & 1;
                const unsigned long long* s = (const unsigned long long*)(hst + row * 16 + half * 8);
                unsigned long long* dp = (unsigned long long*)(hw + (size_t)(row0 + row) * UU + u0 + half * 8);
                __hip_atomic_store(dp,     s[0], __ATOMIC_RELAXED, __HIP_MEMORY_SCOPE_AGENT);
                __hip_atomic_store(dp + 1, s[1], __ATOMIC_RELAXED, __HIP_MEMORY_SCOPE_AGENT);
            }
        }

        // ---- arrive(p): data drained, then flag ----
        if (p < TT) {
            asm volatile("s_waitcnt vmcnt(0)" ::: "memory");
            __syncthreads();
            if (tid == 0) cstu(myArr, (unsigned int)(p + 1));
        }
    }
}

// ---------- final dense: out[b] = sigmoid(h1 . Wd + bd) ----------
__global__ __launch_bounds__(64) void dense_out(
    const unsigned short* __restrict__ h, const float* __restrict__ Wd,
    const float* __restrict__ bd, float* __restrict__ out)
{
    int b = blockIdx.x;
    int lane = threadIdx.x;
    float s = 0.f;
    #pragma unroll
    for (int k = lane; k < UU; k += 64) s += bf2f(h[(size_t)b * UU + k]) * Wd[k];
    #pragma unroll
    for (int off = 32; off > 0; off >>= 1) s += __shfl_down(s, off);
    if (lane == 0) out[b] = sigf(s + bd[0]);
}

extern "C" void kernel_launch(void* const* d_in, const int* in_sizes, int n_in,
                              void* d_out, int out_size, void* d_ws, size_t ws_size,
                              hipStream_t stream) {
    const int*   tokens = (const int*)  d_in[0];
    const float* emb    = (const float*)d_in[1];
    const float* W0     = (const float*)d_in[2];
    const float* U0     = (const float*)d_in[3];
    const float* b0     = (const float*)d_in[4];
    const float* W1     = (const float*)d_in[5];
    const float* U1     = (const float*)d_in[6];
    const float* b1     = (const float*)d_in[7];
    const float* Wd     = (const float*)d_in[8];
    const float* bd     = (const float*)d_in[9];
    float* out = (float*)d_out;

    // ws layout (bytes):
    // [Wt0 3MB][Wt1 4MB][h0 ring x4 1MB][h1 ring x2 0.5MB][bars 32KB][xbf 32MB]
    const size_t oWt0 = 0;
    const size_t oWt1 = (size_t)G4 * 768 * 2;                 // 3,145,728
    const size_t oH0  = oWt1 + (size_t)G4 * 1024 * 2;         // 7,340,032
    const size_t oH1  = oH0 + (size_t)4 * BB * UU * 2;        // +1,048,576
    const size_t oBar = oH1 + (size_t)2 * BB * UU * 2;        // +524,288
    const size_t oX   = oBar + 32768;
    const size_t needFull = oX + (size_t)TT * BB * EE * 2;    // ~42.5 MB
    int use_xbf = (ws_size >= needFull) ? 1 : 0;

    unsigned short* Wt0p = (unsigned short*)((char*)d_ws + oWt0);
    unsigned short* Wt1p = (unsigned short*)((char*)d_ws + oWt1);
    unsigned short* h0p  = (unsigned short*)((char*)d_ws + oH0);
    unsigned short* h1p  = (unsigned short*)((char*)d_ws + oH1);
    unsigned int*   barp = (unsigned int*)  ((char*)d_ws + oBar);
    unsigned short* xbfp = (unsigned short*)((char*)d_ws + oX);

    hipMemsetAsync((char*)d_ws + oH0, 0, oX - oH0, stream);

    wtrans<<<dim3(G4 / 32, EE / 32), dim3(32, 8), 0, stream>>>(W0, EE, Wt0p, 768, 0);
    wtrans<<<dim3(G4 / 32, UU / 32), dim3(32, 8), 0, stream>>>(U0, UU, Wt0p, 768, 256);
    wtrans<<<dim3(G4 / 32, UU / 32), dim3(32, 8), 0, stream>>>(W1, UU, Wt1p, 1024, 0);
    wtrans<<<dim3(G4 / 32, UU / 32), dim3(32, 8), 0, stream>>>(U1, UU, Wt1p, 1024, 512);

    if (use_xbf)
        xgather<<<dim3(BB * TT), dim3(64), 0, stream>>>(tokens, emb, xbfp);

    {
        const size_t shmem = 131072 + 2048 + 256;   // 133,376 B dynamic LDS
        hipFuncSetAttribute((const void*)rnn_persist,
                            hipFuncAttributeMaxDynamicSharedMemorySize, (int)shmem);
        void* args[] = {(void*)&Wt0p, (void*)&Wt1p, (void*)&xbfp,
                        (void*)&tokens, (void*)&emb, (void*)&b0, (void*)&b1,
                        (void*)&h0p, (void*)&h1p, (void*)&barp, (void*)&use_xbf};
        hipLaunchCooperativeKernel((const void*)rnn_persist, dim3(256), dim3(256),
                                   args, shmem, stream);
    }

    dense_out<<<dim3(BB), dim3(64), 0, stream>>>(h1p, Wd, bd, out);   // h1(256) = slot 0
}

// Round 6
// 3092.129 us; speedup vs baseline: 1.0106x; 1.0106x over previous
//
#include <hip/hip_runtime.h>
#include <hip/hip_bf16.h>
#include <math.h>

#define VB 50000
#define EE 256
#define UU 512
#define BB 256
#define TT 256
#define G4 2048

typedef __attribute__((ext_vector_type(8))) short short8;
typedef __attribute__((ext_vector_type(4))) float f32x4;

__device__ __forceinline__ float sigf(float x){ return 1.0f/(1.0f+expf(-x)); }
__device__ __forceinline__ unsigned short f2bf(float f){
    __hip_bfloat16 h = __float2bfloat16(f);   // RNE
    unsigned short s; __builtin_memcpy(&s,&h,2); return s;
}
__device__ __forceinline__ float bf2f(unsigned short u){
    unsigned int x = ((unsigned int)u)<<16; float f; __builtin_memcpy(&f,&x,4); return f;
}

// 16-byte device-coherent load as 2x8B agent-scope relaxed atomics (bypass
// stale per-CU L1 / per-XCD L2; served at the coherent point).
struct AF { unsigned long long a, b; };
__device__ __forceinline__ AF cload16(const unsigned short* p){
    const unsigned long long* q = (const unsigned long long*)p;
    AF r;
    r.a = __hip_atomic_load(q,   __ATOMIC_RELAXED, __HIP_MEMORY_SCOPE_AGENT);
    r.b = __hip_atomic_load(q+1, __ATOMIC_RELAXED, __HIP_MEMORY_SCOPE_AGENT);
    return r;
}
__device__ __forceinline__ short8 af2v(AF x){
    union { unsigned long long u[2]; short8 v; } c; c.u[0]=x.a; c.u[1]=x.b; return c.v;
}
__device__ __forceinline__ unsigned int cldu(const unsigned int* p){
    return __hip_atomic_load(p, __ATOMIC_RELAXED, __HIP_MEMORY_SCOPE_AGENT);
}
__device__ __forceinline__ void cstu(unsigned int* p, unsigned int v){
    __hip_atomic_store(p, v, __ATOMIC_RELAXED, __HIP_MEMORY_SCOPE_AGENT);
}

// ---------- pre-pass: transpose+convert W [rows][2048] fp32 -> out[c][koff+k] bf16 ----------
__global__ __launch_bounds__(256) void wtrans(const float* __restrict__ in, int rows,
                                              unsigned short* __restrict__ out,
                                              int Kout, int koff) {
    __shared__ float tl[32][33];
    int tx = threadIdx.x, ty = threadIdx.y;
    int c0 = blockIdx.x * 32, k0 = blockIdx.y * 32;
    #pragma unroll
    for (int i = 0; i < 4; i++)
        tl[ty + i * 8][tx] = in[(size_t)(k0 + ty + i * 8) * G4 + c0 + tx];
    __syncthreads();
    #pragma unroll
    for (int i = 0; i < 4; i++)
        out[(size_t)(c0 + ty + i * 8) * Kout + koff + k0 + tx] = f2bf(tl[tx][ty + i * 8]);
}

// ---------- pre-pass: gather embeddings -> xbf[t][b][k] bf16 ----------
__global__ __launch_bounds__(64) void xgather(const int* __restrict__ tokens,
                                              const float* __restrict__ emb,
                                              unsigned short* __restrict__ xbf) {
    int flat = blockIdx.x;
    int b = flat & 255, t = flat >> 8;
    int tok = tokens[b * TT + t];
    float4 v = ((const float4*)(emb + (size_t)tok * EE))[threadIdx.x];
    ushort4 o;
    o.x = f2bf(v.x); o.y = f2bf(v.y); o.z = f2bf(v.z); o.w = f2bf(v.w);
    ((ushort4*)(xbf + ((size_t)t * BB + b) * EE))[threadIdx.x] = o;
}

// ---------- persistent 2-layer LSTM ----------
// 4 groups x 64 blocks; group g owns batch rows [g*64, g*64+64).
// local 0..31 = layer0 (K=768: x|h0), 32..63 = layer1 (K=1024: h0|h1); 16 u's/block.
// Weights LDS-resident. c-state in registers. h via agent-scope relaxed atomics.
// DIRECT FLAG POLLING (no leader/go): wave 0 of every block polls all 64
// producer arrival flags (lane L -> flag of block L), ballots, syncthreads.
// Ready conditions (flag value f = phases finished):
//   L0 @ p: L0 flags >= p (h0(p) ready)  AND  L1 flags >= p-2 (h0 ring-4 flow ctl)
//   L1 @ p: L0 flags >= p (h0(p) ready)  AND  L1 flags >= p (h1(p-1) ready;
//            also proves readers of h1(p-2) are done -> h1 ring-2 safe)
__global__ __launch_bounds__(256, 1) void rnn_persist(
    const unsigned short* __restrict__ Wt0,   // [2048][768]  bf16 [col][k]
    const unsigned short* __restrict__ Wt1,   // [2048][1024]
    const unsigned short* __restrict__ xbf,   // [256][256][256] bf16 (or unused)
    const int* __restrict__ tokens, const float* __restrict__ emb,
    const float* __restrict__ b0v, const float* __restrict__ b1v,
    unsigned short* __restrict__ h0buf,       // [4][256][512] bf16 ring
    unsigned short* __restrict__ h1buf,       // [2][256][512] bf16 ring
    unsigned int* __restrict__ bars,          // per group 1024 uints (4KB)
    int use_xbf)
{
    extern __shared__ char smem[];
    unsigned short* wl  = (unsigned short*)smem;               // frag-ordered weights (<=128KB)
    unsigned short* hst = (unsigned short*)(smem + 131072);    // 64x16 h staging, stride 24 (3KB)
    int*            tokl = (int*)(smem + 131072 + 3072);       // 64 ints

    const int tid   = threadIdx.x;
    const int bid   = blockIdx.x;
    const int g     = bid >> 6;
    const int local = bid & 63;
    const int layer = local >> 5;
    const int u0    = (local & 31) * 16;
    const int row0  = g * 64;
    const int K     = layer ? 1024 : 768;
    const int KT    = K / 32;                  // 24 or 32 k-tiles
    const unsigned short* Wt = layer ? Wt1 : Wt0;
    const float* bR = layer ? b1v : b0v;

    // ---- fill LDS weights, frag-contiguous: chunk i = ((gate*KT+kt)*64 + (n*4+q)) ----
    const int nch = 4 * KT * 64;
    for (int i = tid; i < nch; i += 256) {
        int q  = i & 3;
        int n  = (i >> 2) & 15;
        int t2 = i >> 6;
        int kt = t2 % KT, gate = t2 / KT;
        const unsigned short* src = Wt + (size_t)(gate * UU + u0 + n) * K + kt * 32 + q * 8;
        *(short8*)(wl + (size_t)i * 8) = *(const short8*)src;
    }

    float gb[4];
    #pragma unroll
    for (int gate = 0; gate < 4; gate++) gb[gate] = bR[gate * UU + u0 + (tid & 15)];
    float cst[4] = {0.f, 0.f, 0.f, 0.f};

    const int lane = tid & 63;
    const int w    = tid >> 6;
    const int n16  = lane & 15;
    const int q    = lane >> 4;
    const int q8   = q * 8;
    const int myrow = row0 + w * 16 + n16;
    const unsigned short* wlane = wl + (n16 * 4 + q) * 8;   // + (gate*KT+kt)*512 shorts

    // flag region for this group: flag(local) at 16B stride
    unsigned int* flg = bars + (size_t)g * 1024;
    unsigned int* myFlag = flg + local * 4;

    const size_t HS = (size_t)BB * UU;

    __syncthreads();   // wl ready

    for (int p = 0; p <= TT; p++) {
        const bool active = layer ? (p >= 1) : (p < TT);
        const bool wait_needed = layer ? (p >= 1) : (p < TT);

        f32x4 acc[4];
        #pragma unroll
        for (int gate = 0; gate < 4; gate++)
            acc[gate] = (f32x4){gb[gate], gb[gate], gb[gate], gb[gate]};

        // ---- L0 x-part precompute (static inputs only) BEFORE the wait ----
        if (layer == 0 && p < TT) {
            if (!use_xbf) {
                if (tid < 64) tokl[tid] = tokens[(size_t)(row0 + tid) * TT + p];
                __syncthreads();
                const float* ep = emb + (size_t)tokl[w * 16 + n16] * EE + q8;
                #pragma unroll
                for (int kt = 0; kt < 8; kt++) {
                    float4 f0 = *(const float4*)(ep + kt * 32);
                    float4 f1 = *(const float4*)(ep + kt * 32 + 4);
                    union { unsigned short s[8]; short8 v; } u;
                    u.s[0]=f2bf(f0.x); u.s[1]=f2bf(f0.y); u.s[2]=f2bf(f0.z); u.s[3]=f2bf(f0.w);
                    u.s[4]=f2bf(f1.x); u.s[5]=f2bf(f1.y); u.s[6]=f2bf(f1.z); u.s[7]=f2bf(f1.w);
                    #pragma unroll
                    for (int gate = 0; gate < 4; gate++) {
                        short8 bv = *(const short8*)(wlane + (size_t)(gate * KT + kt) * 512);
                        acc[gate] = __builtin_amdgcn_mfma_f32_16x16x32_bf16(u.v, bv, acc[gate], 0, 0, 0);
                    }
                }
            } else {
                const unsigned short* xp = xbf + ((size_t)p * BB + myrow) * EE + q8;
                #pragma unroll
                for (int kt = 0; kt < 8; kt++) {
                    short8 av = *(const short8*)(xp + kt * 32);
                    #pragma unroll
                    for (int gate = 0; gate < 4; gate++) {
                        short8 bv = *(const short8*)(wlane + (size_t)(gate * KT + kt) * 512);
                        acc[gate] = __builtin_amdgcn_mfma_f32_16x16x32_bf16(av, bv, acc[gate], 0, 0, 0);
                    }
                }
            }
        }

        // ---- direct-poll wait: wave 0, lane L polls flag of block L ----
        if (wait_needed) {
            if (tid < 64) {
                const unsigned int* fp = flg + tid * 4;
                const int thr = (layer == 0 && tid >= 32) ? (p - 2) : p;
                for (;;) {
                    bool bad = ((int)cldu(fp) < thr);
                    if (__ballot(bad) == 0ULL) break;
                    __builtin_amdgcn_s_sleep(1);
                }
            }
            __syncthreads();
        }

        // ---- dynamic (h-dependent) part ----
        if (active) {
            const unsigned short* h0r = h0buf + (size_t)(p & 3) * HS;
            unsigned short* hw;

            if (layer) {
                const unsigned short* h1r = h1buf + (size_t)((p + 1) & 1) * HS;  // h1(p-1)
                hw = h1buf + (size_t)(p & 1) * HS;
                const unsigned short* a0 = h0r + (size_t)myrow * UU + q8;
                const unsigned short* a1 = h1r + (size_t)myrow * UU + q8;
                AF ab[2][16];
                #pragma unroll
                for (int i = 0; i < 16; i++) ab[0][i] = cload16(a0 + i * 32);
                #pragma unroll
                for (int i = 0; i < 16; i++) ab[1][i] = cload16(a1 + i * 32);
                #pragma unroll
                for (int half = 0; half < 2; half++) {
                    #pragma unroll
                    for (int i = 0; i < 16; i++) {
                        int kt = half * 16 + i;
                        short8 av = af2v(ab[half][i]);
                        #pragma unroll
                        for (int gate = 0; gate < 4; gate++) {
                            short8 bv = *(const short8*)(wlane + (size_t)(gate * KT + kt) * 512);
                            acc[gate] = __builtin_amdgcn_mfma_f32_16x16x32_bf16(av, bv, acc[gate], 0, 0, 0);
                        }
                    }
                }
            } else {
                hw = h0buf + (size_t)((p + 1) & 3) * HS;
                const unsigned short* ah = h0r + (size_t)myrow * UU + q8;
                AF ab[16];
                #pragma unroll
                for (int i = 0; i < 16; i++) ab[i] = cload16(ah + i * 32);
                #pragma unroll
                for (int i = 0; i < 16; i++) {
                    int kt = 8 + i;
                    short8 av = af2v(ab[i]);
                    #pragma unroll
                    for (int gate = 0; gate < 4; gate++) {
                        short8 bv = *(const short8*)(wlane + (size_t)(gate * KT + kt) * 512);
                        acc[gate] = __builtin_amdgcn_mfma_f32_16x16x32_bf16(av, bv, acc[gate], 0, 0, 0);
                    }
                }
            }

            // gating (D layout: col=n16 -> u, row=q*4+r); stage h to LDS (stride 24)
            #pragma unroll
            for (int r = 0; r < 4; r++) {
                float zi = acc[0][r];
                float zf = acc[1][r];
                float zg = acc[2][r];
                float zo = acc[3][r];
                float cn = sigf(zf) * cst[r] + sigf(zi) * tanhf(zg);
                cst[r] = cn;
                hst[(w * 16 + q * 4 + r) * 24 + n16] = f2bf(sigf(zo) * tanhf(cn));
            }
            __syncthreads();   // block-uniform
            if (tid < 128) {   // coalesced coherent store: 128 threads x 16B
                int row = tid >> 1, half = tid & 1;
                const unsigned long long* s = (const unsigned long long*)(hst + row * 24 + half * 8);
                unsigned long long* dp = (unsigned long long*)(hw + (size_t)(row0 + row) * UU + u0 + half * 8);
                __hip_atomic_store(dp,     s[0], __ATOMIC_RELAXED, __HIP_MEMORY_SCOPE_AGENT);
                __hip_atomic_store(dp + 1, s[1], __ATOMIC_RELAXED, __HIP_MEMORY_SCOPE_AGENT);
            }
        }

        // ---- arrive(p): data drained, then flag ----
        if (p < TT) {
            asm volatile("s_waitcnt vmcnt(0)" ::: "memory");
            __syncthreads();
            if (tid == 0) cstu(myFlag, (unsigned int)(p + 1));
        }
    }
}

// ---------- final dense: out[b] = sigmoid(h1 . Wd + bd) ----------
__global__ __launch_bounds__(64) void dense_out(
    const unsigned short* __restrict__ h, const float* __restrict__ Wd,
    const float* __restrict__ bd, float* __restrict__ out)
{
    int b = blockIdx.x;
    int lane = threadIdx.x;
    float s = 0.f;
    #pragma unroll
    for (int k = lane; k < UU; k += 64) s += bf2f(h[(size_t)b * UU + k]) * Wd[k];
    #pragma unroll
    for (int off = 32; off > 0; off >>= 1) s += __shfl_down(s, off);
    if (lane == 0) out[b] = sigf(s + bd[0]);
}

extern "C" void kernel_launch(void* const* d_in, const int* in_sizes, int n_in,
                              void* d_out, int out_size, void* d_ws, size_t ws_size,
                              hipStream_t stream) {
    const int*   tokens = (const int*)  d_in[0];
    const float* emb    = (const float*)d_in[1];
    const float* W0     = (const float*)d_in[2];
    const float* U0     = (const float*)d_in[3];
    const float* b0     = (const float*)d_in[4];
    const float* W1     = (const float*)d_in[5];
    const float* U1     = (const float*)d_in[6];
    const float* b1     = (const float*)d_in[7];
    const float* Wd     = (const float*)d_in[8];
    const float* bd     = (const float*)d_in[9];
    float* out = (float*)d_out;

    // ws layout (bytes):
    // [Wt0 3MB][Wt1 4MB][h0 ring x4 1MB][h1 ring x2 0.5MB][bars 32KB][xbf 32MB]
    const size_t oWt0 = 0;
    const size_t oWt1 = (size_t)G4 * 768 * 2;                 // 3,145,728
    const size_t oH0  = oWt1 + (size_t)G4 * 1024 * 2;         // 7,340,032
    const size_t oH1  = oH0 + (size_t)4 * BB * UU * 2;        // +1,048,576
    const size_t oBar = oH1 + (size_t)2 * BB * UU * 2;        // +524,288
    const size_t oX   = oBar + 32768;
    const size_t needFull = oX + (size_t)TT * BB * EE * 2;    // ~42.5 MB
    int use_xbf = (ws_size >= needFull) ? 1 : 0;

    unsigned short* Wt0p = (unsigned short*)((char*)d_ws + oWt0);
    unsigned short* Wt1p = (unsigned short*)((char*)d_ws + oWt1);
    unsigned short* h0p  = (unsigned short*)((char*)d_ws + oH0);
    unsigned short* h1p  = (unsigned short*)((char*)d_ws + oH1);
    unsigned int*   barp = (unsigned int*)  ((char*)d_ws + oBar);
    unsigned short* xbfp = (unsigned short*)((char*)d_ws + oX);

    hipMemsetAsync((char*)d_ws + oH0, 0, oX - oH0, stream);

    wtrans<<<dim3(G4 / 32, EE / 32), dim3(32, 8), 0, stream>>>(W0, EE, Wt0p, 768, 0);
    wtrans<<<dim3(G4 / 32, UU / 32), dim3(32, 8), 0, stream>>>(U0, UU, Wt0p, 768, 256);
    wtrans<<<dim3(G4 / 32, UU / 32), dim3(32, 8), 0, stream>>>(W1, UU, Wt1p, 1024, 0);
    wtrans<<<dim3(G4 / 32, UU / 32), dim3(32, 8), 0, stream>>>(U1, UU, Wt1p, 1024, 512);

    if (use_xbf)
        xgather<<<dim3(BB * TT), dim3(64), 0, stream>>>(tokens, emb, xbfp);

    {
        const size_t shmem = 131072 + 3072 + 256;   // 134,400 B dynamic LDS
        hipFuncSetAttribute((const void*)rnn_persist,
                            hipFuncAttributeMaxDynamicSharedMemorySize, (int)shmem);
        void* args[] = {(void*)&Wt0p, (void*)&Wt1p, (void*)&xbfp,
                        (void*)&tokens, (void*)&emb, (void*)&b0, (void*)&b1,
                        (void*)&h0p, (void*)&h1p, (void*)&barp, (void*)&use_xbf};
        hipLaunchCooperativeKernel((const void*)rnn_persist, dim3(256), dim3(256),
                                   args, shmem, stream);
    }

    dense_out<<<dim3(BB), dim3(64), 0, stream>>>(h1p, Wd, bd, out);   // h1(256) = slot 0
}

// Round 7
// 3003.613 us; speedup vs baseline: 1.0404x; 1.0295x over previous
//
#include <hip/hip_runtime.h>
#include <hip/hip_bf16.h>
#include <math.h>

#define VB 50000
#define EE 256
#define UU 512
#define BB 256
#define TT 256
#define G4 2048

typedef __attribute__((ext_vector_type(8))) short short8;
typedef __attribute__((ext_vector_type(4))) float f32x4;

__device__ __forceinline__ float sigf(float x){ return 1.0f/(1.0f+expf(-x)); }
__device__ __forceinline__ unsigned short f2bf(float f){
    __hip_bfloat16 h = __float2bfloat16(f);   // RNE
    unsigned short s; __builtin_memcpy(&s,&h,2); return s;
}
__device__ __forceinline__ float bf2f(unsigned short u){
    unsigned int x = ((unsigned int)u)<<16; float f; __builtin_memcpy(&f,&x,4); return f;
}

// 16-byte device-coherent load as 2x8B agent-scope relaxed atomics (bypass
// stale per-CU L1 / per-XCD L2; served at the coherent point).
struct AF { unsigned long long a, b; };
__device__ __forceinline__ AF cload16(const unsigned short* p){
    const unsigned long long* q = (const unsigned long long*)p;
    AF r;
    r.a = __hip_atomic_load(q,   __ATOMIC_RELAXED, __HIP_MEMORY_SCOPE_AGENT);
    r.b = __hip_atomic_load(q+1, __ATOMIC_RELAXED, __HIP_MEMORY_SCOPE_AGENT);
    return r;
}
__device__ __forceinline__ short8 af2v(AF x){
    union { unsigned long long u[2]; short8 v; } c; c.u[0]=x.a; c.u[1]=x.b; return c.v;
}
__device__ __forceinline__ unsigned int cldu(const unsigned int* p){
    return __hip_atomic_load(p, __ATOMIC_RELAXED, __HIP_MEMORY_SCOPE_AGENT);
}
__device__ __forceinline__ void cstu(unsigned int* p, unsigned int v){
    __hip_atomic_store(p, v, __ATOMIC_RELAXED, __HIP_MEMORY_SCOPE_AGENT);
}

// ---------- pre-pass: transpose+convert W [rows][2048] fp32 -> out[c][koff+k] bf16 ----------
__global__ __launch_bounds__(256) void wtrans(const float* __restrict__ in, int rows,
                                              unsigned short* __restrict__ out,
                                              int Kout, int koff) {
    __shared__ float tl[32][33];
    int tx = threadIdx.x, ty = threadIdx.y;
    int c0 = blockIdx.x * 32, k0 = blockIdx.y * 32;
    #pragma unroll
    for (int i = 0; i < 4; i++)
        tl[ty + i * 8][tx] = in[(size_t)(k0 + ty + i * 8) * G4 + c0 + tx];
    __syncthreads();
    #pragma unroll
    for (int i = 0; i < 4; i++)
        out[(size_t)(c0 + ty + i * 8) * Kout + koff + k0 + tx] = f2bf(tl[tx][ty + i * 8]);
}

// ---------- pre-pass: gather embeddings -> xbf[t][b][k] bf16 ----------
__global__ __launch_bounds__(64) void xgather(const int* __restrict__ tokens,
                                              const float* __restrict__ emb,
                                              unsigned short* __restrict__ xbf) {
    int flat = blockIdx.x;
    int b = flat & 255, t = flat >> 8;
    int tok = tokens[b * TT + t];
    float4 v = ((const float4*)(emb + (size_t)tok * EE))[threadIdx.x];
    ushort4 o;
    o.x = f2bf(v.x); o.y = f2bf(v.y); o.z = f2bf(v.z); o.w = f2bf(v.w);
    ((ushort4*)(xbf + ((size_t)t * BB + b) * EE))[threadIdx.x] = o;
}

// ---------- persistent 2-layer LSTM ----------
// 4 groups x 64 blocks; group g owns batch rows [g*64, g*64+64).
// local 0..31 = layer0 (K=768: x|h0), 32..63 = layer1 (K=1024: h0|h1); 16 u's/block.
// Weights LDS-resident. c-state in registers. h via agent-scope relaxed atomics.
// PER-WAVE flag polling (each wave polls all 64 flags itself -> starts its own
// A-prologue immediately; own-block flag in the poll set makes hst reuse safe).
// A-loads: register-bounded 2-stage pipeline, 8 AFs (32 VGPRs) per stage ->
// consume of stage s waits vmcnt(16) while stage s+1 stays in flight.
__global__ __launch_bounds__(256, 1) void rnn_persist(
    const unsigned short* __restrict__ Wt0,   // [2048][768]  bf16 [col][k]
    const unsigned short* __restrict__ Wt1,   // [2048][1024]
    const unsigned short* __restrict__ xbf,   // [256][256][256] bf16 (or unused)
    const int* __restrict__ tokens, const float* __restrict__ emb,
    const float* __restrict__ b0v, const float* __restrict__ b1v,
    unsigned short* __restrict__ h0buf,       // [4][256][512] bf16 ring
    unsigned short* __restrict__ h1buf,       // [2][256][512] bf16 ring
    unsigned int* __restrict__ bars,          // per group 1024 uints (4KB)
    int use_xbf)
{
    extern __shared__ char smem[];
    unsigned short* wl  = (unsigned short*)smem;               // frag-ordered weights (<=128KB)
    unsigned short* hst = (unsigned short*)(smem + 131072);    // 64x16 h staging, stride 24 (3KB)
    int*            tokl = (int*)(smem + 131072 + 3072);       // 64 ints

    const int tid   = threadIdx.x;
    const int bid   = blockIdx.x;
    const int g     = bid >> 6;
    const int local = bid & 63;
    const int layer = local >> 5;
    const int u0    = (local & 31) * 16;
    const int row0  = g * 64;
    const int K     = layer ? 1024 : 768;
    const int KT    = K / 32;                  // 24 or 32 k-tiles
    const unsigned short* Wt = layer ? Wt1 : Wt0;
    const float* bR = layer ? b1v : b0v;

    // ---- fill LDS weights, frag-contiguous: chunk i = ((gate*KT+kt)*64 + (n*4+q)) ----
    const int nch = 4 * KT * 64;
    for (int i = tid; i < nch; i += 256) {
        int q  = i & 3;
        int n  = (i >> 2) & 15;
        int t2 = i >> 6;
        int kt = t2 % KT, gate = t2 / KT;
        const unsigned short* src = Wt + (size_t)(gate * UU + u0 + n) * K + kt * 32 + q * 8;
        *(short8*)(wl + (size_t)i * 8) = *(const short8*)src;
    }

    float gb[4];
    #pragma unroll
    for (int gate = 0; gate < 4; gate++) gb[gate] = bR[gate * UU + u0 + (tid & 15)];
    float cst[4] = {0.f, 0.f, 0.f, 0.f};

    const int lane = tid & 63;
    const int w    = tid >> 6;
    const int n16  = lane & 15;
    const int q    = lane >> 4;
    const int q8   = q * 8;
    const int myrow = row0 + w * 16 + n16;
    const unsigned short* wlane = wl + (n16 * 4 + q) * 8;   // + (gate*KT+kt)*512 shorts

    // flag region for this group: flag(local) at 16B stride
    unsigned int* flg = bars + (size_t)g * 1024;
    unsigned int* myFlag = flg + local * 4;
    // per-lane poll target: lane L polls flag of block L
    const unsigned int* pollp = flg + lane * 4;
    const int pollSlack = (layer == 0 && lane >= 32) ? 2 : 0;  // L0 waits L1>=p-2

    const size_t HS = (size_t)BB * UU;

    __syncthreads();   // wl ready

    for (int p = 0; p <= TT; p++) {
        const bool active = layer ? (p >= 1) : (p < TT);
        const bool wait_needed = layer ? (p >= 1) : (p < TT);

        f32x4 acc[4];
        #pragma unroll
        for (int gate = 0; gate < 4; gate++)
            acc[gate] = (f32x4){gb[gate], gb[gate], gb[gate], gb[gate]};

        // ---- L0 x-part precompute (static inputs only) BEFORE the wait ----
        if (layer == 0 && p < TT) {
            if (!use_xbf) {
                if (tid < 64) tokl[tid] = tokens[(size_t)(row0 + tid) * TT + p];
                __syncthreads();
                const float* ep = emb + (size_t)tokl[w * 16 + n16] * EE + q8;
                #pragma unroll
                for (int kt = 0; kt < 8; kt++) {
                    float4 f0 = *(const float4*)(ep + kt * 32);
                    float4 f1 = *(const float4*)(ep + kt * 32 + 4);
                    union { unsigned short s[8]; short8 v; } u;
                    u.s[0]=f2bf(f0.x); u.s[1]=f2bf(f0.y); u.s[2]=f2bf(f0.z); u.s[3]=f2bf(f0.w);
                    u.s[4]=f2bf(f1.x); u.s[5]=f2bf(f1.y); u.s[6]=f2bf(f1.z); u.s[7]=f2bf(f1.w);
                    #pragma unroll
                    for (int gate = 0; gate < 4; gate++) {
                        short8 bv = *(const short8*)(wlane + (size_t)(gate * KT + kt) * 512);
                        acc[gate] = __builtin_amdgcn_mfma_f32_16x16x32_bf16(u.v, bv, acc[gate], 0, 0, 0);
                    }
                }
            } else {
                const unsigned short* xp = xbf + ((size_t)p * BB + myrow) * EE + q8;
                #pragma unroll
                for (int kt = 0; kt < 8; kt++) {
                    short8 av = *(const short8*)(xp + kt * 32);
                    #pragma unroll
                    for (int gate = 0; gate < 4; gate++) {
                        short8 bv = *(const short8*)(wlane + (size_t)(gate * KT + kt) * 512);
                        acc[gate] = __builtin_amdgcn_mfma_f32_16x16x32_bf16(av, bv, acc[gate], 0, 0, 0);
                    }
                }
            }
        }

        // ---- per-wave direct poll: lane L polls flag of block L, no sync after ----
        if (wait_needed) {
            const int thr = p - pollSlack;
            for (;;) {
                bool bad = ((int)cldu(pollp) < thr);
                if (__ballot(bad) == 0ULL) break;
                __builtin_amdgcn_s_sleep(1);
            }
        }

        // ---- dynamic (h-dependent) part: register-bounded A pipeline ----
        if (active) {
            const unsigned short* h0r = h0buf + (size_t)(p & 3) * HS;
            unsigned short* hw;

            if (layer) {
                const unsigned short* h1r = h1buf + (size_t)((p + 1) & 1) * HS;  // h1(p-1)
                hw = h1buf + (size_t)(p & 1) * HS;
                const unsigned short* a0 = h0r + (size_t)myrow * UU + q8;
                const unsigned short* a1 = h1r + (size_t)myrow * UU + q8;
                AF ab[2][8];
                #pragma unroll
                for (int i = 0; i < 8; i++) ab[0][i] = cload16(a0 + i * 32);  // stage 0
                #pragma unroll
                for (int s = 0; s < 4; s++) {
                    const int cur = s & 1, nxt = cur ^ 1;
                    if (s < 3) {
                        #pragma unroll
                        for (int i = 0; i < 8; i++) {
                            int kt = (s + 1) * 8 + i;
                            const unsigned short* ap = (kt < 16) ? (a0 + kt * 32)
                                                                 : (a1 + (kt - 16) * 32);
                            ab[nxt][i] = cload16(ap);
                        }
                    }
                    #pragma unroll
                    for (int i = 0; i < 8; i++) {
                        int kt = s * 8 + i;
                        short8 av = af2v(ab[cur][i]);
                        #pragma unroll
                        for (int gate = 0; gate < 4; gate++) {
                            short8 bv = *(const short8*)(wlane + (size_t)(gate * KT + kt) * 512);
                            acc[gate] = __builtin_amdgcn_mfma_f32_16x16x32_bf16(av, bv, acc[gate], 0, 0, 0);
                        }
                    }
                }
            } else {
                hw = h0buf + (size_t)((p + 1) & 3) * HS;
                const unsigned short* ah = h0r + (size_t)myrow * UU + q8;
                AF ab[2][8];
                #pragma unroll
                for (int i = 0; i < 8; i++) ab[0][i] = cload16(ah + i * 32);  // kt 8..15
                #pragma unroll
                for (int s = 0; s < 2; s++) {
                    const int cur = s & 1, nxt = cur ^ 1;
                    if (s < 1) {
                        #pragma unroll
                        for (int i = 0; i < 8; i++)
                            ab[nxt][i] = cload16(ah + (8 + i) * 32);          // kt 16..23
                    }
                    #pragma unroll
                    for (int i = 0; i < 8; i++) {
                        int kt = 8 + s * 8 + i;
                        short8 av = af2v(ab[cur][i]);
                        #pragma unroll
                        for (int gate = 0; gate < 4; gate++) {
                            short8 bv = *(const short8*)(wlane + (size_t)(gate * KT + kt) * 512);
                            acc[gate] = __builtin_amdgcn_mfma_f32_16x16x32_bf16(av, bv, acc[gate], 0, 0, 0);
                        }
                    }
                }
            }

            // gating (D layout: col=n16 -> u, row=q*4+r); stage h to LDS (stride 24)
            #pragma unroll
            for (int r = 0; r < 4; r++) {
                float zi = acc[0][r];
                float zf = acc[1][r];
                float zg = acc[2][r];
                float zo = acc[3][r];
                float cn = sigf(zf) * cst[r] + sigf(zi) * tanhf(zg);
                cst[r] = cn;
                hst[(w * 16 + q * 4 + r) * 24 + n16] = f2bf(sigf(zo) * tanhf(cn));
            }
            __syncthreads();   // hst complete (block-uniform path)
            if (tid < 128) {   // coalesced coherent store: 128 threads x 16B
                int row = tid >> 1, half = tid & 1;
                const unsigned long long* s = (const unsigned long long*)(hst + row * 24 + half * 8);
                unsigned long long* dp = (unsigned long long*)(hw + (size_t)(row0 + row) * UU + u0 + half * 8);
                __hip_atomic_store(dp,     s[0], __ATOMIC_RELAXED, __HIP_MEMORY_SCOPE_AGENT);
                __hip_atomic_store(dp + 1, s[1], __ATOMIC_RELAXED, __HIP_MEMORY_SCOPE_AGENT);
            }
        }

        // ---- arrive(p): every wave drains its own vmem, then tid0 flags ----
        if (p < TT) {
            asm volatile("s_waitcnt vmcnt(0)" ::: "memory");
            __syncthreads();
            if (tid == 0) cstu(myFlag, (unsigned int)(p + 1));
        }
    }
}

// ---------- final dense: out[b] = sigmoid(h1 . Wd + bd) ----------
__global__ __launch_bounds__(64) void dense_out(
    const unsigned short* __restrict__ h, const float* __restrict__ Wd,
    const float* __restrict__ bd, float* __restrict__ out)
{
    int b = blockIdx.x;
    int lane = threadIdx.x;
    float s = 0.f;
    #pragma unroll
    for (int k = lane; k < UU; k += 64) s += bf2f(h[(size_t)b * UU + k]) * Wd[k];
    #pragma unroll
    for (int off = 32; off > 0; off >>= 1) s += __shfl_down(s, off);
    if (lane == 0) out[b] = sigf(s + bd[0]);
}

extern "C" void kernel_launch(void* const* d_in, const int* in_sizes, int n_in,
                              void* d_out, int out_size, void* d_ws, size_t ws_size,
                              hipStream_t stream) {
    const int*   tokens = (const int*)  d_in[0];
    const float* emb    = (const float*)d_in[1];
    const float* W0     = (const float*)d_in[2];
    const float* U0     = (const float*)d_in[3];
    const float* b0     = (const float*)d_in[4];
    const float* W1     = (const float*)d_in[5];
    const float* U1     = (const float*)d_in[6];
    const float* b1     = (const float*)d_in[7];
    const float* Wd     = (const float*)d_in[8];
    const float* bd     = (const float*)d_in[9];
    float* out = (float*)d_out;

    // ws layout (bytes):
    // [Wt0 3MB][Wt1 4MB][h0 ring x4 1MB][h1 ring x2 0.5MB][bars 32KB][xbf 32MB]
    const size_t oWt0 = 0;
    const size_t oWt1 = (size_t)G4 * 768 * 2;                 // 3,145,728
    const size_t oH0  = oWt1 + (size_t)G4 * 1024 * 2;         // 7,340,032
    const size_t oH1  = oH0 + (size_t)4 * BB * UU * 2;        // +1,048,576
    const size_t oBar = oH1 + (size_t)2 * BB * UU * 2;        // +524,288
    const size_t oX   = oBar + 32768;
    const size_t needFull = oX + (size_t)TT * BB * EE * 2;    // ~42.5 MB
    int use_xbf = (ws_size >= needFull) ? 1 : 0;

    unsigned short* Wt0p = (unsigned short*)((char*)d_ws + oWt0);
    unsigned short* Wt1p = (unsigned short*)((char*)d_ws + oWt1);
    unsigned short* h0p  = (unsigned short*)((char*)d_ws + oH0);
    unsigned short* h1p  = (unsigned short*)((char*)d_ws + oH1);
    unsigned int*   barp = (unsigned int*)  ((char*)d_ws + oBar);
    unsigned short* xbfp = (unsigned short*)((char*)d_ws + oX);

    hipMemsetAsync((char*)d_ws + oH0, 0, oX - oH0, stream);

    wtrans<<<dim3(G4 / 32, EE / 32), dim3(32, 8), 0, stream>>>(W0, EE, Wt0p, 768, 0);
    wtrans<<<dim3(G4 / 32, UU / 32), dim3(32, 8), 0, stream>>>(U0, UU, Wt0p, 768, 256);
    wtrans<<<dim3(G4 / 32, UU / 32), dim3(32, 8), 0, stream>>>(W1, UU, Wt1p, 1024, 0);
    wtrans<<<dim3(G4 / 32, UU / 32), dim3(32, 8), 0, stream>>>(U1, UU, Wt1p, 1024, 512);

    if (use_xbf)
        xgather<<<dim3(BB * TT), dim3(64), 0, stream>>>(tokens, emb, xbfp);

    {
        const size_t shmem = 131072 + 3072 + 256;   // 134,400 B dynamic LDS
        hipFuncSetAttribute((const void*)rnn_persist,
                            hipFuncAttributeMaxDynamicSharedMemorySize, (int)shmem);
        void* args[] = {(void*)&Wt0p, (void*)&Wt1p, (void*)&xbfp,
                        (void*)&tokens, (void*)&emb, (void*)&b0, (void*)&b1,
                        (void*)&h0p, (void*)&h1p, (void*)&barp, (void*)&use_xbf};
        hipLaunchCooperativeKernel((const void*)rnn_persist, dim3(256), dim3(256),
                                   args, shmem, stream);
    }

    dense_out<<<dim3(BB), dim3(64), 0, stream>>>(h1p, Wd, bd, out);   // h1(256) = slot 0
}